// Round 4
// baseline (174.729 us; speedup 1.0000x reference)
//
#include <hip/hip_runtime.h>

#define T_TOK 32768   // B*S
#define NQ    8
#define FFN   2048
#define EMB   512
#define BM    128
#define BN    128
#define BK    32
#define NCHUNK (FFN / BK)   // 64

typedef __attribute__((ext_vector_type(8)))  short short8;
typedef __attribute__((ext_vector_type(16))) float f32x16;
typedef __attribute__((ext_vector_type(2)))  unsigned int u32x2;

__device__ __forceinline__ unsigned short f2bf(float f) {
  unsigned int u = __float_as_uint(f);
  u += 0x7fffu + ((u >> 16) & 1u);
  return (unsigned short)(u >> 16);
}

__device__ __forceinline__ unsigned pk2bf(float lo, float hi) {
#if __has_builtin(__builtin_amdgcn_cvt_pk_bf16_f32)
  typedef __attribute__((ext_vector_type(2))) __bf16 bf2;
  bf2 p = __builtin_amdgcn_cvt_pk_bf16_f32(lo, hi);
  return *(unsigned*)&p;
#else
  return (unsigned)f2bf(lo) | ((unsigned)f2bf(hi) << 16);
#endif
}

// ---------------------------------------------------------------------------
// prep_all: tiled transpose W2[FFN][EMB] fp32 -> w2t[EMB][FFN] bf16,
//           plus w1t[f][i] bf16 from W1[i][f] (blockIdx.x==0 column).
// ---------------------------------------------------------------------------
__global__ void prep_all(const float* __restrict__ W1,
                         const float* __restrict__ W2,
                         unsigned short* __restrict__ w1t,
                         unsigned short* __restrict__ w2t) {
  __shared__ float t[32][33];
  const int kb = blockIdx.x * 32;   // FFN tile
  const int nb = blockIdx.y * 32;   // EMB tile
  const int c = threadIdx.x & 31, r0 = threadIdx.x >> 5;
#pragma unroll
  for (int p = 0; p < 4; ++p) {
    int r = r0 + p * 8;
    t[r][c] = W2[(size_t)(kb + r) * EMB + nb + c];
  }
  __syncthreads();
#pragma unroll
  for (int p = 0; p < 4; ++p) {
    int r = r0 + p * 8;
    w2t[(size_t)(nb + r) * FFN + kb + c] = f2bf(t[c][r]);
  }
  if (blockIdx.x == 0) {
    const int base = blockIdx.y * 1024 + threadIdx.x * 4;
#pragma unroll
    for (int e = 0; e < 4; ++e) {
      int idx = base + e;
      int f = idx >> 3, i = idx & 7;
      w1t[idx] = f2bf(W1[i * FFN + f]);
    }
  }
}

// ---------------------------------------------------------------------------
// Fused main, R7 (= R6 with corrected permlane32_swap routing).
//   - GEMM1: ONE mfma_f32_32x32x16_bf16 per chunk (K=16, q=8..15 zero-padded;
//     bias pre-loaded into the MFMA C-in). D[f][tok]: tok=lane&31 already
//     matches GEMM2's A-frag row mapping -> the f-redistribution is a pure
//     lane<->lane+32 exchange via permlane32_swap.
//     Derivation (C/D map row=(r&3)+8*(r>>2)+4*hi, col=lane&31):
//       Q[p]=pk(c1[2p],c1[2p+1]) holds f-pairs; A-word j needs f=8*hi+2j.
//       s = swap(Qa, Qb): s[0]={Qa@lo, Qb@lo}, s[1]={Qa@hi, Qb@hi}
//       -> word0=s(Q0,Q2)[0], word2=s(Q0,Q2)[1], word1/3 from (Q1,Q3);
//          afB same with Q4..Q7.  (R6 had args+outputs inverted -> FAIL.)
//   - GEMM2: 8 mfma 32x32x16 per chunk; B-frags from XOR-swizzled w2 LDS
//     (R5's staging, measured conflict-free).
//   - A/B positional-agreement note: GEMM2 needs only that A and B place the
//     same f at the same (half,elem) slot; both use f = 8*hi + e.
//   - LDS = w2 dbuf only: 16384 B; one barrier/chunk; vmcnt(0) drain covered
//     by a full chunk of compute.
// ---------------------------------------------------------------------------
__global__ __launch_bounds__(256, 4) void ffq_main(
    const float* __restrict__ x,
    const float* __restrict__ theta,
    const unsigned short* __restrict__ w1t,
    const float* __restrict__ b1,
    const unsigned short* __restrict__ w2t,
    const float* __restrict__ b2,
    float* __restrict__ out) {

  __shared__ __align__(16) unsigned short w2_lds[2][BN * BK];   // 16384 B

  const int tid  = threadIdx.x;
  const int wave = tid >> 6;
  const int lane = tid & 63;
  const int nl   = lane & 31;      // n / tok / f-row index within 32
  const int hi   = lane >> 5;      // which 32-lane half
  const int tok0 = blockIdx.x * BM;
  const int n0   = blockIdx.y * BN;

  // ---- bq: GEMM1 B-frag B[k=q][n=tok]; upper-half k-slots are zero ----
  float cth[8];
  {
    const float4* tp = (const float4*)theta;
    float4 t0 = tp[0], t1 = tp[1];
    cth[0] = __cosf(t0.x); cth[1] = __cosf(t0.y);
    cth[2] = __cosf(t0.z); cth[3] = __cosf(t0.w);
    cth[4] = __cosf(t1.x); cth[5] = __cosf(t1.y);
    cth[6] = __cosf(t1.z); cth[7] = __cosf(t1.w);
  }
  short8 bq;
  {
    const float4* xp =
        (const float4*)(x + (size_t)(tok0 + wave * 32 + nl) * NQ);
    float4 x0 = xp[0], x1 = xp[1];
    float q0 = __cosf(x0.x) * cth[0], q1 = __cosf(x0.y) * cth[1];
    float q2 = __cosf(x0.z) * cth[2], q3 = __cosf(x0.w) * cth[3];
    float q4 = __cosf(x1.x) * cth[4], q5 = __cosf(x1.y) * cth[5];
    float q6 = __cosf(x1.z) * cth[6], q7 = __cosf(x1.w) * cth[7];
    uint4 uu;
    uu.x = pk2bf(q0, q1); uu.y = pk2bf(q2, q3);
    uu.z = pk2bf(q4, q5); uu.w = pk2bf(q6, q7);
    if (hi) { uu.x = 0; uu.y = 0; uu.z = 0; uu.w = 0; }
    bq = *(short8*)&uu;
  }

  // ---- w2 staging: linear LDS dest, pre-swizzled global source ----
  // stored 16B-chunk c of row r holds global chunk c ^ ((r>>1)&3).
  const int st_gc = (tid & 3) ^ ((tid >> 3) & 3);
  auto stage_w2 = [&](int kc_, int b_) {
    const int k0_ = kc_ * BK;
#pragma unroll
    for (int issue = 0; issue < 2; ++issue) {
      const int r = issue * 64 + (tid >> 2);
      __builtin_amdgcn_global_load_lds(
          (const __attribute__((address_space(1))) void*)(
              w2t + (size_t)(n0 + r) * FFN + k0_ + st_gc * 8),
          (__attribute__((address_space(3))) void*)(
              &w2_lds[b_][issue * 2048 + tid * 8]),
          16, 0, 0);
    }
  };

  // ---- GEMM2 B-frag read bases: row nl, k-chunk (ks*2+hi) ^ ((nl>>1)&3) --
  const int swz = (nl >> 1) & 3;
  const unsigned short* rd0[2];
  const unsigned short* rd1[2];
#pragma unroll
  for (int b = 0; b < 2; ++b) {
    rd0[b] = &w2_lds[b][nl * 32 + ((0 + hi) ^ swz) * 8];
    rd1[b] = &w2_lds[b][nl * 32 + ((2 + hi) ^ swz) * 8];
  }

  f32x16 acc[4];
#pragma unroll
  for (int nt = 0; nt < 4; ++nt)
#pragma unroll
    for (int r = 0; r < 16; ++r) acc[nt][r] = 0.f;

  // ---- GEMM1 for chunk `nc` -> af fragments (A[tok][f] for GEMM2) ----
  short8 afA[2], afB[2];
  auto gemm1 = [&](short8 aw, const float4* b4, short8& oA, short8& oB) {
    f32x16 c1;
#pragma unroll
    for (int r = 0; r < 16; ++r) c1[r] = b4[r >> 2][r & 3];  // bias as C-in
    c1 = __builtin_amdgcn_mfma_f32_32x32x16_bf16(aw, bq, c1, 0, 0, 0);
    unsigned Q[8];
#pragma unroll
    for (int p = 0; p < 8; ++p) {
      float lo = c1[2 * p]     > 0.f ? c1[2 * p]     : 0.f;
      float hl = c1[2 * p + 1] > 0.f ? c1[2 * p + 1] : 0.f;
      Q[p] = pk2bf(lo, hl);
    }
    // f-redistribution across halves (corrected):
    //   word0 = {Q0@lo, Q2@lo}, word2 = {Q0@hi, Q2@hi}, etc.
    u32x2 s0 = __builtin_amdgcn_permlane32_swap(Q[0], Q[2], false, false);
    u32x2 s1 = __builtin_amdgcn_permlane32_swap(Q[1], Q[3], false, false);
    u32x2 s2 = __builtin_amdgcn_permlane32_swap(Q[4], Q[6], false, false);
    u32x2 s3 = __builtin_amdgcn_permlane32_swap(Q[5], Q[7], false, false);
    uint4 uA; uA.x = s0[0]; uA.y = s1[0]; uA.z = s0[1]; uA.w = s1[1];
    uint4 uB; uB.x = s2[0]; uB.y = s3[0]; uB.z = s2[1]; uB.w = s3[1];
    oA = *(short8*)&uA;
    oB = *(short8*)&uB;
  };

  // ---- prologue: chunk 0 loads + stage; GEMM1(0) while stage flies ----
  {
    short8 aw0 = *(const short8*)(w1t + (size_t)nl * NQ);
    float4 b40[4];
#pragma unroll
    for (int g2 = 0; g2 < 4; ++g2)
      b40[g2] = *(const float4*)(b1 + 8 * g2 + 4 * hi);
    stage_w2(0, 0);
    gemm1(aw0, b40, afA[0], afB[0]);
  }

#pragma unroll 2
  for (int kc = 0; kc < NCHUNK; ++kc) {
    const int b  = kc & 1;
    const int nc = (kc + 1 < NCHUNK) ? kc + 1 : NCHUNK - 1;  // clamp: uniform

    // stage(kc) had a full chunk to land -> near-free drain
    asm volatile("s_waitcnt vmcnt(0)" ::: "memory");
    __builtin_amdgcn_s_barrier();   // w2[b] ready; all readers of w2[b^1] done
    __builtin_amdgcn_sched_barrier(0);

    // ---- loads for GEMM1(nc), BEFORE stage (retire without full drain) ----
    short8 aw = *(const short8*)(w1t + (size_t)(nc * 32 + nl) * NQ);
    float4 b4[4];
#pragma unroll
    for (int g2 = 0; g2 < 4; ++g2)
      b4[g2] = *(const float4*)(b1 + nc * 32 + 8 * g2 + 4 * hi);

    stage_w2(nc, b ^ 1);            // prefetch next chunk (stays in flight)

    // ---- GEMM2(kc): 8 x 32x32x16, B-frags from swizzled LDS ----
    __builtin_amdgcn_s_setprio(1);
    {
      short8 bf[4];
#pragma unroll
      for (int nt = 0; nt < 4; ++nt)
        bf[nt] = *(const short8*)(rd0[b] + nt * 1024);
#pragma unroll
      for (int nt = 0; nt < 4; ++nt)
        acc[nt] = __builtin_amdgcn_mfma_f32_32x32x16_bf16(
            afA[b], bf[nt], acc[nt], 0, 0, 0);
#pragma unroll
      for (int nt = 0; nt < 4; ++nt)
        bf[nt] = *(const short8*)(rd1[b] + nt * 1024);
#pragma unroll
      for (int nt = 0; nt < 4; ++nt)
        acc[nt] = __builtin_amdgcn_mfma_f32_32x32x16_bf16(
            afB[b], bf[nt], acc[nt], 0, 0, 0);
    }
    __builtin_amdgcn_s_setprio(0);

    // ---- GEMM1(nc): interleaves with GEMM2 above (no sched fence) ----
    gemm1(aw, b4, afA[b ^ 1], afB[b ^ 1]);
  }

  // drain the clamped last prefetch before LDS goes away
  asm volatile("s_waitcnt vmcnt(0)" ::: "memory");

  // ---- epilogue: + b2, fp32 store ----
#pragma unroll
  for (int nt = 0; nt < 4; ++nt) {
    const int col = n0 + nt * 32 + nl;
    const float bv = b2[col];
    const int rbase = tok0 + wave * 32 + 4 * hi;
#pragma unroll
    for (int g2 = 0; g2 < 4; ++g2)
#pragma unroll
      for (int rr = 0; rr < 4; ++rr)
        out[(size_t)(rbase + 8 * g2 + rr) * EMB + col] =
            acc[nt][4 * g2 + rr] + bv;
  }
}

extern "C" void kernel_launch(void* const* d_in, const int* in_sizes, int n_in,
                              void* d_out, int out_size, void* d_ws, size_t ws_size,
                              hipStream_t stream) {
  const float* x     = (const float*)d_in[0];
  const float* theta = (const float*)d_in[1];
  const float* W1    = (const float*)d_in[2];
  const float* b1    = (const float*)d_in[3];
  const float* W2    = (const float*)d_in[4];
  const float* b2    = (const float*)d_in[5];
  float* out = (float*)d_out;

  unsigned short* w1t = (unsigned short*)d_ws;       // 16384 bf16
  unsigned short* w2t = w1t + FFN * NQ;              // 1048576 bf16

  prep_all<<<dim3(FFN / 32, EMB / 32), 256, 0, stream>>>(W1, W2, w1t, w2t);

  dim3 grid(T_TOK / BM, EMB / BN);  // (256, 4) = 1024 blocks = 4/CU resident
  ffq_main<<<grid, 256, 0, stream>>>(x, theta, w1t, b1, w2t, b2, out);
}